// Round 7
// baseline (422.010 us; speedup 1.0000x reference)
//
#include <hip/hip_runtime.h>
#include <hip/hip_bf16.h>
#include <cstdint>

typedef unsigned short u16;
typedef __attribute__((ext_vector_type(8))) short s16x8;
typedef __attribute__((ext_vector_type(4))) float f32x4;
typedef __attribute__((ext_vector_type(4))) unsigned short u16x4;

#define MFMA16(a, b, c) __builtin_amdgcn_mfma_f32_16x16x32_bf16((a), (b), (c), 0, 0, 0)

__device__ __forceinline__ u16 f2bf(float f) {
  union { float f; uint32_t u; } x; x.f = f;
  uint32_t u = x.u;
  return (u16)((u + 0x7fffu + ((u >> 16) & 1u)) >> 16);
}

__device__ __forceinline__ void gll16(const void* gsrc, void* ldst) {
  __builtin_amdgcn_global_load_lds(
      (const __attribute__((address_space(1))) uint32_t*)(uintptr_t)gsrc,
      (__attribute__((address_space(3))) uint32_t*)(uintptr_t)ldst, 16, 0, 0);
}

// ---------------- fused f32 -> bf16 conversion (one launch for all 7 tensors)
__global__ __launch_bounds__(256) void cvt_all_kernel(
    const f32x4* __restrict__ q, const f32x4* __restrict__ k, const f32x4* __restrict__ v,
    const f32x4* __restrict__ wq, const f32x4* __restrict__ wk,
    const f32x4* __restrict__ wv, const f32x4* __restrict__ wo,
    u16x4* __restrict__ dst) {
  int i = blockIdx.x * 256 + threadIdx.x;  // 0 .. 4194303
  int r = i >> 18;                         // 262144-element chunks
  const f32x4* src;
  int off;
  if (r < 4)       { src = q;  off = 0; }
  else if (r < 8)  { src = k;  off = 1048576; }
  else if (r < 12) { src = v;  off = 2097152; }
  else if (r == 12){ src = wq; off = 3145728; }
  else if (r == 13){ src = wk; off = 3407872; }
  else if (r == 14){ src = wv; off = 3670016; }
  else             { src = wo; off = 3932160; }
  f32x4 val = src[i - off];
  u16x4 o;
  #pragma unroll
  for (int j = 0; j < 4; ++j) o[j] = f2bf(val[j]);
  dst[i] = o;
}

// ---------------- fused QKV projection GEMM (bf16 in via gll16) ------------
__global__ __launch_bounds__(256) void proj_qkv_kernel(
    const u16* __restrict__ Xq, const u16* __restrict__ Xk, const u16* __restrict__ Xv,
    const u16* __restrict__ Wq, const u16* __restrict__ Wk, const u16* __restrict__ Wv,
    const float* __restrict__ bq, const float* __restrict__ bk, const float* __restrict__ bv,
    u16* __restrict__ Qo, u16* __restrict__ Ko, u16* __restrict__ Vo) {
  __shared__ __align__(16) u16 Asm[128 * 64];
  __shared__ __align__(16) u16 Bsm[128 * 64];

  const int z = blockIdx.z;
  const u16* X = (z == 0) ? Xq : (z == 1) ? Xk : Xv;
  const u16* W = (z == 0) ? Wq : (z == 1) ? Wk : Wv;
  const float* bias = (z == 0) ? bq : (z == 1) ? bk : bv;

  const int t = threadIdx.x;
  const int lane = t & 63;
  const int l15 = lane & 15, lg = lane >> 4;
  const int wid = t >> 6;
  const int wr = wid >> 1, wc = wid & 1;
  const int m0 = blockIdx.x * 128, n0 = blockIdx.y * 128;

  f32x4 acc[4][4] = {};

  for (int kt = 0; kt < 16; ++kt) {
    __syncthreads();
    #pragma unroll
    for (int i = 0; i < 4; ++i) {
      int tt = i * 256 + t;
      int row = tt >> 3;
      int sg = (tt & 7) ^ (row & 7);
      gll16(X + (size_t)(m0 + row) * 1024 + kt * 64 + sg * 8, Asm + tt * 8);
    }
    #pragma unroll
    for (int i = 0; i < 4; ++i) {
      int tt = i * 256 + t;
      int row = tt >> 3;
      int sg = (tt & 7) ^ (row & 7);
      gll16(W + (size_t)(n0 + row) * 1024 + kt * 64 + sg * 8, Bsm + tt * 8);
    }
    __syncthreads();
    #pragma unroll
    for (int kk = 0; kk < 2; ++kk) {
      s16x8 af[4], bf[4];
      #pragma unroll
      for (int mi = 0; mi < 4; ++mi) {
        int row = wr * 64 + mi * 16 + l15;
        int g = (lg + 4 * kk) ^ (row & 7);
        af[mi] = *(const s16x8*)(Asm + row * 64 + g * 8);
      }
      #pragma unroll
      for (int ni = 0; ni < 4; ++ni) {
        int row = wc * 64 + ni * 16 + l15;
        int g = (lg + 4 * kk) ^ (row & 7);
        bf[ni] = *(const s16x8*)(Bsm + row * 64 + g * 8);
      }
      #pragma unroll
      for (int mi = 0; mi < 4; ++mi)
        #pragma unroll
        for (int ni = 0; ni < 4; ++ni)
          acc[mi][ni] = MFMA16(af[mi], bf[ni], acc[mi][ni]);
    }
  }

  #pragma unroll
  for (int ni = 0; ni < 4; ++ni) {
    const int col = n0 + wc * 64 + ni * 16 + l15;
    const int h = col >> 6, d = col & 63;
    const float bval = bias[col];
    #pragma unroll
    for (int mi = 0; mi < 4; ++mi) {
      const int row0 = m0 + wr * 64 + mi * 16 + lg * 4;
      const int bb = row0 >> 11, s0 = row0 & 2047;
      if (z == 2) {
        u16x4 pk;
        #pragma unroll
        for (int r = 0; r < 4; ++r) pk[r] = f2bf(acc[mi][ni][r] + bval);
        *(u16x4*)(Vo + ((size_t)(bb * 16 + h) * 64 + d) * 2048 + s0) = pk;
      } else {
        u16* dst = (z == 0) ? Qo : Ko;
        #pragma unroll
        for (int r = 0; r < 4; ++r)
          dst[((size_t)(bb * 16 + h) * 2048 + (s0 + r)) * 64 + d] =
              f2bf(acc[mi][ni][r] + bval);
      }
    }
  }
}

// ---------------- flash attention, deep pipeline + real occupancy ----------
// logits = (Q.K^T + position_bias) * 0.125 + mask ; online softmax ; O = P.V
// Per iter: barrier -> mask(t) regs (issued before STAGE: in-order vmcnt
// retirement, so mask-wait doesn't drain HBM stage loads) -> STAGE K/V(t+1)
// -> pb(t+1) regs (consumed after next barrier: full phase of cover) ->
// compute(t). __launch_bounds__(256,4) caps VGPR+AGPR (unified file!) at 128
// -> 4 blocks/CU = 16 waves/CU.
__global__ __launch_bounds__(256, 4) void attn_kernel(
    const u16* __restrict__ Qw, const u16* __restrict__ Kw, const u16* __restrict__ Vtw,
    const float* __restrict__ pb, const float* __restrict__ mk, u16* __restrict__ Out) {
  __shared__ __align__(16) u16 Ksm[2][64 * 64];
  __shared__ __align__(16) u16 Vsm[2][64 * 64];
  __shared__ __align__(16) u16 Psm[4 * 16 * 64];  // per-wave, XOR-swizzled

  const int qt = blockIdx.x >> 1;  // 0..31
  const int b  = blockIdx.x & 1;   // batch
  const int h  = blockIdx.y;       // 0..15
  const int t = threadIdx.x;
  const int lane = t & 63;
  const int wid = t >> 6;
  const int l15 = lane & 15, lg = lane >> 4;
  const size_t bh = (size_t)b * 16 + h;

  const u16* kbase = Kw + bh * 2048 * 64;
  const u16* vbase = Vtw + bh * 64 * 2048;

  // Q A-fragments (kept in registers across all kv tiles)
  const int qrow_a = qt * 64 + wid * 16 + l15;
  const u16* qptr = Qw + (bh * 2048 + (size_t)qrow_a) * 64 + lg * 8;
  const s16x8 qf0 = *(const s16x8*)(qptr);
  const s16x8 qf1 = *(const s16x8*)(qptr + 32);

  const int qrow_c = qt * 64 + wid * 16 + lg * 4;  // C-layout base q row
  const float* pb_base = pb + ((size_t)h * 2048 + qrow_c) * 2048;
  const float* mk_base = mk + ((size_t)b * 2048 + qrow_c) * 2048;

  const float LOG2E = 1.4426950408889634f;
  const float C1 = 0.125f * 1.4426950408889634f;

  f32x4 oacc[4] = {};
  float m_r[4], l_r[4];
  #pragma unroll
  for (int r = 0; r < 4; ++r) { m_r[r] = -3.0e38f; l_r[r] = 0.f; }

  float pbA[4][4], pbB[4][4];

#define STAGE(KT, BI)                                                          \
  {                                                                            \
    const int kv0_ = (KT) * 64;                                                \
    _Pragma("unroll")                                                          \
    for (int i = 0; i < 2; ++i) {                                              \
      int tt = i * 256 + t;                                                    \
      int row = tt >> 3;                                                       \
      int sg = (tt & 7) ^ (row & 7);                                           \
      gll16(kbase + (size_t)(kv0_ + row) * 64 + sg * 8, &Ksm[BI][tt * 8]);     \
      gll16(vbase + (size_t)row * 2048 + kv0_ + sg * 8, &Vsm[BI][tt * 8]);     \
    }                                                                          \
  }

#define LOADPB(KT, PBV)                                                        \
  {                                                                            \
    const int kv0_ = (KT) * 64;                                                \
    _Pragma("unroll")                                                          \
    for (int f = 0; f < 4; ++f)                                                \
      _Pragma("unroll")                                                        \
      for (int r = 0; r < 4; ++r)                                              \
        PBV[f][r] = pb_base[(size_t)r * 2048 + kv0_ + f * 16 + l15];           \
  }

// One pipeline step: consume K/V buf BI and pb regs PBC for tile KT; prefetch
// STAGE(KT+1) into BI^1 and pb(KT+1) into PBN.
#define ITER(KT, BI, PBC, PBN)                                                 \
  {                                                                            \
    const int kv0 = (KT) * 64;                                                 \
    __syncthreads(); /* drains stage(KT)+pb(KT), issued one phase ago */       \
    /* mask(t) first: L3-resident, retires without waiting on new stage */     \
    float mkv[4][4];                                                           \
    _Pragma("unroll")                                                          \
    for (int f = 0; f < 4; ++f)                                                \
      _Pragma("unroll")                                                        \
      for (int r = 0; r < 4; ++r)                                              \
        mkv[f][r] = mk_base[(size_t)r * 2048 + kv0 + f * 16 + l15];            \
    if ((KT) < 31) {                                                           \
      STAGE((KT) + 1, (BI) ^ 1);                                               \
      LOADPB((KT) + 1, PBN);                                                   \
    }                                                                          \
    /* S = Q.K^T */                                                            \
    f32x4 sf[4] = {};                                                          \
    _Pragma("unroll")                                                          \
    for (int kk = 0; kk < 2; ++kk) {                                           \
      s16x8 q = kk ? qf1 : qf0;                                                \
      _Pragma("unroll")                                                        \
      for (int f = 0; f < 4; ++f) {                                            \
        int row = f * 16 + l15;                                                \
        int g = (lg + 4 * kk) ^ (row & 7);                                     \
        s16x8 kf = *(const s16x8*)(&Ksm[BI][row * 64 + g * 8]);                \
        sf[f] = MFMA16(q, kf, sf[f]);                                          \
      }                                                                        \
    }                                                                          \
    /* logits in exp2 domain */                                                \
    float pmax[4];                                                             \
    _Pragma("unroll")                                                          \
    for (int r = 0; r < 4; ++r) pmax[r] = -3.0e38f;                            \
    _Pragma("unroll")                                                          \
    for (int f = 0; f < 4; ++f) {                                              \
      _Pragma("unroll")                                                        \
      for (int r = 0; r < 4; ++r) {                                            \
        float lv = fmaf(sf[f][r] + PBC[f][r], C1, mkv[f][r] * LOG2E);          \
        sf[f][r] = lv;                                                         \
        pmax[r] = fmaxf(pmax[r], lv);                                          \
      }                                                                        \
    }                                                                          \
    _Pragma("unroll")                                                          \
    for (int off = 1; off < 16; off <<= 1) {                                   \
      _Pragma("unroll")                                                        \
      for (int r = 0; r < 4; ++r)                                              \
        pmax[r] = fmaxf(pmax[r], __shfl_xor(pmax[r], off));                    \
    }                                                                          \
    float corr[4], rsum[4];                                                    \
    _Pragma("unroll")                                                          \
    for (int r = 0; r < 4; ++r) {                                              \
      float mn = fmaxf(m_r[r], pmax[r]);                                       \
      corr[r] = exp2f(m_r[r] - mn);                                            \
      m_r[r] = mn;                                                             \
      rsum[r] = 0.f;                                                           \
    }                                                                          \
    _Pragma("unroll")                                                          \
    for (int f = 0; f < 4; ++f) {                                              \
      _Pragma("unroll")                                                        \
      for (int r = 0; r < 4; ++r) {                                            \
        float p = exp2f(sf[f][r] - m_r[r]);                                    \
        sf[f][r] = p;                                                          \
        rsum[r] += p;                                                          \
      }                                                                        \
    }                                                                          \
    _Pragma("unroll")                                                          \
    for (int off = 1; off < 16; off <<= 1) {                                   \
      _Pragma("unroll")                                                        \
      for (int r = 0; r < 4; ++r) rsum[r] += __shfl_xor(rsum[r], off);         \
    }                                                                          \
    _Pragma("unroll")                                                          \
    for (int r = 0; r < 4; ++r) l_r[r] = l_r[r] * corr[r] + rsum[r];           \
    _Pragma("unroll")                                                          \
    for (int f = 0; f < 4; ++f) {                                              \
      _Pragma("unroll")                                                        \
      for (int r = 0; r < 4; ++r) oacc[f][r] *= corr[r];                       \
    }                                                                          \
    /* P -> bf16 -> per-wave LDS, XOR group swizzle (0 conflicts) */           \
    u16* pw = Psm + wid * 1024;                                                \
    _Pragma("unroll")                                                          \
    for (int f = 0; f < 4; ++f) {                                              \
      _Pragma("unroll")                                                        \
      for (int r = 0; r < 4; ++r) {                                            \
        int prow = lg * 4 + r;                                                 \
        int c = f * 16 + l15;                                                  \
        pw[prow * 64 + (((c >> 3) ^ (prow & 7)) * 8) + (c & 7)] =              \
            f2bf(sf[f][r]);                                                    \
      }                                                                        \
    }                                                                          \
    /* O += P.V */                                                             \
    _Pragma("unroll")                                                          \
    for (int kk = 0; kk < 2; ++kk) {                                           \
      int pg = (kk * 4 + lg) ^ (l15 & 7);                                      \
      s16x8 pf = *(const s16x8*)(pw + l15 * 64 + pg * 8);                      \
      _Pragma("unroll")                                                        \
      for (int f = 0; f < 4; ++f) {                                            \
        int row = f * 16 + l15;                                                \
        int g = (lg + 4 * kk) ^ (row & 7);                                     \
        s16x8 vf = *(const s16x8*)(&Vsm[BI][row * 64 + g * 8]);                \
        oacc[f] = MFMA16(pf, vf, oacc[f]);                                     \
      }                                                                        \
    }                                                                          \
  }

  STAGE(0, 0);
  LOADPB(0, pbA);

  for (int kt2 = 0; kt2 < 16; ++kt2) {
    ITER(2 * kt2,     0, pbA, pbB);
    ITER(2 * kt2 + 1, 1, pbB, pbA);
  }
#undef ITER
#undef LOADPB
#undef STAGE

  #pragma unroll
  for (int r = 0; r < 4; ++r) {
    float inv = 1.f / l_r[r];
    #pragma unroll
    for (int f = 0; f < 4; ++f) {
      int q = qrow_c + r;
      Out[((size_t)b * 2048 + q) * 1024 + h * 64 + f * 16 + l15] =
          f2bf(oacc[f][r] * inv);
    }
  }
}

// ---------------- output projection GEMM ----------------
__global__ __launch_bounds__(256) void oproj_kernel(
    const u16* __restrict__ A, const u16* __restrict__ W,
    const float* __restrict__ bias, float* __restrict__ out) {
  __shared__ __align__(16) u16 Asm[128 * 64];
  __shared__ __align__(16) u16 Bsm[128 * 64];

  const int t = threadIdx.x;
  const int lane = t & 63;
  const int l15 = lane & 15, lg = lane >> 4;
  const int wid = t >> 6;
  const int wr = wid >> 1, wc = wid & 1;
  const int m0 = blockIdx.x * 128, n0 = blockIdx.y * 128;

  f32x4 acc[4][4] = {};

  for (int kt = 0; kt < 16; ++kt) {
    __syncthreads();
    #pragma unroll
    for (int i = 0; i < 4; ++i) {
      int tt = i * 256 + t;
      int row = tt >> 3;
      int sg = (tt & 7) ^ (row & 7);
      gll16(A + (size_t)(m0 + row) * 1024 + kt * 64 + sg * 8, Asm + tt * 8);
    }
    #pragma unroll
    for (int i = 0; i < 4; ++i) {
      int tt = i * 256 + t;
      int row = tt >> 3;
      int sg = (tt & 7) ^ (row & 7);
      gll16(W + (size_t)(n0 + row) * 1024 + kt * 64 + sg * 8, Bsm + tt * 8);
    }
    __syncthreads();
    #pragma unroll
    for (int kk = 0; kk < 2; ++kk) {
      s16x8 af[4], bf[4];
      #pragma unroll
      for (int mi = 0; mi < 4; ++mi) {
        int row = wr * 64 + mi * 16 + l15;
        int g = (lg + 4 * kk) ^ (row & 7);
        af[mi] = *(const s16x8*)(Asm + row * 64 + g * 8);
      }
      #pragma unroll
      for (int ni = 0; ni < 4; ++ni) {
        int row = wc * 64 + ni * 16 + l15;
        int g = (lg + 4 * kk) ^ (row & 7);
        bf[ni] = *(const s16x8*)(Bsm + row * 64 + g * 8);
      }
      #pragma unroll
      for (int mi = 0; mi < 4; ++mi)
        #pragma unroll
        for (int ni = 0; ni < 4; ++ni)
          acc[mi][ni] = MFMA16(af[mi], bf[ni], acc[mi][ni]);
    }
  }

  #pragma unroll
  for (int ni = 0; ni < 4; ++ni) {
    const int col = n0 + wc * 64 + ni * 16 + l15;
    const float bval = bias[col];
    #pragma unroll
    for (int mi = 0; mi < 4; ++mi) {
      const int row0 = m0 + wr * 64 + mi * 16 + lg * 4;
      #pragma unroll
      for (int r = 0; r < 4; ++r)
        out[(size_t)(row0 + r) * 1024 + col] = acc[mi][ni][r] + bval;
    }
  }
}

extern "C" void kernel_launch(void* const* d_in, const int* in_sizes, int n_in,
                              void* d_out, int out_size, void* d_ws, size_t ws_size,
                              hipStream_t stream) {
  const float* query = (const float*)d_in[0];
  const float* key_i = (const float*)d_in[1];
  const float* value = (const float*)d_in[2];
  const float* mask  = (const float*)d_in[3];
  const float* pbias = (const float*)d_in[4];
  const float* wq = (const float*)d_in[5];
  const float* bq = (const float*)d_in[6];
  const float* wk = (const float*)d_in[7];
  const float* bk = (const float*)d_in[8];
  const float* wv = (const float*)d_in[9];
  const float* bv = (const float*)d_in[10];
  const float* wo = (const float*)d_in[11];
  const float* bo = (const float*)d_in[12];
  float* out = (float*)d_out;

  uint8_t* ws = (uint8_t*)d_ws;
  u16* Xq = (u16*)(ws + 0);          // 4096x1024 bf16
  u16* Xk = (u16*)(ws + 8388608);
  u16* Xv = (u16*)(ws + 16777216);
  u16* Wq = (u16*)(ws + 25165824);   // 1024x1024 bf16 each
  u16* Wk = (u16*)(ws + 27262976);
  u16* Wv = (u16*)(ws + 29360128);
  u16* Wo = (u16*)(ws + 31457280);
  u16* Qw = (u16*)(ws + 33554432);   // [B,H,S,D] bf16
  u16* Kw = (u16*)(ws + 41943040);   // [B,H,S,D]
  u16* Vt = (u16*)(ws + 50331648);   // [B,H,D,S]
  u16* Aw = (u16*)(ws + 58720256);   // [B,S,H*D]

  cvt_all_kernel<<<16384, 256, 0, stream>>>(
      (const f32x4*)query, (const f32x4*)key_i, (const f32x4*)value,
      (const f32x4*)wq, (const f32x4*)wk, (const f32x4*)wv, (const f32x4*)wo,
      (u16x4*)Xq);

  proj_qkv_kernel<<<dim3(32, 8, 3), 256, 0, stream>>>(Xq, Xk, Xv, Wq, Wk, Wv,
                                                      bq, bk, bv, Qw, Kw, Vt);
  attn_kernel<<<dim3(64, 16), 256, 0, stream>>>(Qw, Kw, Vt, pbias, mask, Aw);
  oproj_kernel<<<dim3(32, 8), 256, 0, stream>>>(Aw, Wo, bo, out);
}

// Round 8
// 270.731 us; speedup vs baseline: 1.5588x; 1.5588x over previous
//
#include <hip/hip_runtime.h>
#include <hip/hip_bf16.h>
#include <cstdint>

typedef unsigned short u16;
typedef __attribute__((ext_vector_type(8))) short s16x8;
typedef __attribute__((ext_vector_type(4))) float f32x4;
typedef __attribute__((ext_vector_type(4))) unsigned short u16x4;

#define MFMA16(a, b, c) __builtin_amdgcn_mfma_f32_16x16x32_bf16((a), (b), (c), 0, 0, 0)

__device__ __forceinline__ u16 f2bf(float f) {
  union { float f; uint32_t u; } x; x.f = f;
  uint32_t u = x.u;
  return (u16)((u + 0x7fffu + ((u >> 16) & 1u)) >> 16);
}

__device__ __forceinline__ void gll16(const void* gsrc, void* ldst) {
  __builtin_amdgcn_global_load_lds(
      (const __attribute__((address_space(1))) uint32_t*)(uintptr_t)gsrc,
      (__attribute__((address_space(3))) uint32_t*)(uintptr_t)ldst, 16, 0, 0);
}

// ---------------- fused f32 -> bf16 conversion (one launch for all 7 tensors)
__global__ __launch_bounds__(256) void cvt_all_kernel(
    const f32x4* __restrict__ q, const f32x4* __restrict__ k, const f32x4* __restrict__ v,
    const f32x4* __restrict__ wq, const f32x4* __restrict__ wk,
    const f32x4* __restrict__ wv, const f32x4* __restrict__ wo,
    u16x4* __restrict__ dst) {
  int i = blockIdx.x * 256 + threadIdx.x;  // 0 .. 4194303
  int r = i >> 18;                         // 262144-element chunks
  const f32x4* src;
  int off;
  if (r < 4)       { src = q;  off = 0; }
  else if (r < 8)  { src = k;  off = 1048576; }
  else if (r < 12) { src = v;  off = 2097152; }
  else if (r == 12){ src = wq; off = 3145728; }
  else if (r == 13){ src = wk; off = 3407872; }
  else if (r == 14){ src = wv; off = 3670016; }
  else             { src = wo; off = 3932160; }
  f32x4 val = src[i - off];
  u16x4 o;
  #pragma unroll
  for (int j = 0; j < 4; ++j) o[j] = f2bf(val[j]);
  dst[i] = o;
}

// ---------------- fused QKV projection GEMM (bf16 in via gll16) ------------
__global__ __launch_bounds__(256) void proj_qkv_kernel(
    const u16* __restrict__ Xq, const u16* __restrict__ Xk, const u16* __restrict__ Xv,
    const u16* __restrict__ Wq, const u16* __restrict__ Wk, const u16* __restrict__ Wv,
    const float* __restrict__ bq, const float* __restrict__ bk, const float* __restrict__ bv,
    u16* __restrict__ Qo, u16* __restrict__ Ko, u16* __restrict__ Vo) {
  __shared__ __align__(16) u16 Asm[128 * 64];
  __shared__ __align__(16) u16 Bsm[128 * 64];

  const int z = blockIdx.z;
  const u16* X = (z == 0) ? Xq : (z == 1) ? Xk : Xv;
  const u16* W = (z == 0) ? Wq : (z == 1) ? Wk : Wv;
  const float* bias = (z == 0) ? bq : (z == 1) ? bk : bv;

  const int t = threadIdx.x;
  const int lane = t & 63;
  const int l15 = lane & 15, lg = lane >> 4;
  const int wid = t >> 6;
  const int wr = wid >> 1, wc = wid & 1;
  const int m0 = blockIdx.x * 128, n0 = blockIdx.y * 128;

  f32x4 acc[4][4] = {};

  for (int kt = 0; kt < 16; ++kt) {
    __syncthreads();
    #pragma unroll
    for (int i = 0; i < 4; ++i) {
      int tt = i * 256 + t;
      int row = tt >> 3;
      int sg = (tt & 7) ^ (row & 7);
      gll16(X + (size_t)(m0 + row) * 1024 + kt * 64 + sg * 8, Asm + tt * 8);
    }
    #pragma unroll
    for (int i = 0; i < 4; ++i) {
      int tt = i * 256 + t;
      int row = tt >> 3;
      int sg = (tt & 7) ^ (row & 7);
      gll16(W + (size_t)(n0 + row) * 1024 + kt * 64 + sg * 8, Bsm + tt * 8);
    }
    __syncthreads();
    #pragma unroll
    for (int kk = 0; kk < 2; ++kk) {
      s16x8 af[4], bf[4];
      #pragma unroll
      for (int mi = 0; mi < 4; ++mi) {
        int row = wr * 64 + mi * 16 + l15;
        int g = (lg + 4 * kk) ^ (row & 7);
        af[mi] = *(const s16x8*)(Asm + row * 64 + g * 8);
      }
      #pragma unroll
      for (int ni = 0; ni < 4; ++ni) {
        int row = wc * 64 + ni * 16 + l15;
        int g = (lg + 4 * kk) ^ (row & 7);
        bf[ni] = *(const s16x8*)(Bsm + row * 64 + g * 8);
      }
      #pragma unroll
      for (int mi = 0; mi < 4; ++mi)
        #pragma unroll
        for (int ni = 0; ni < 4; ++ni)
          acc[mi][ni] = MFMA16(af[mi], bf[ni], acc[mi][ni]);
    }
  }

  #pragma unroll
  for (int ni = 0; ni < 4; ++ni) {
    const int col = n0 + wc * 64 + ni * 16 + l15;
    const int h = col >> 6, d = col & 63;
    const float bval = bias[col];
    #pragma unroll
    for (int mi = 0; mi < 4; ++mi) {
      const int row0 = m0 + wr * 64 + mi * 16 + lg * 4;
      const int bb = row0 >> 11, s0 = row0 & 2047;
      if (z == 2) {
        u16x4 pk;
        #pragma unroll
        for (int r = 0; r < 4; ++r) pk[r] = f2bf(acc[mi][ni][r] + bval);
        *(u16x4*)(Vo + ((size_t)(bb * 16 + h) * 64 + d) * 2048 + s0) = pk;
      } else {
        u16* dst = (z == 0) ? Qo : Ko;
        #pragma unroll
        for (int r = 0; r < 4; ++r)
          dst[((size_t)(bb * 16 + h) * 2048 + (s0 + r)) * 64 + d] =
              f2bf(acc[mi][ni][r] + bval);
      }
    }
  }
}

// ---------------- flash attention, pb+mask folded into MFMA C-operand ------
// logits = (Q.K^T + pb) * 0.125 + mask  ==  0.125 * (S + pb + 8*mask)
// So preload pbmk = pb + 8*mask (16 regs) and feed it as the C input of the
// first QK^T MFMA round: the matrix pipe does the add for free. Saves 16 regs
// (vs pbv+mkv) and ~32 VALU ops/iter. pbmk(t+1) reloads right after the kk=0
// MFMAs consume pbmk(t); the next barrier's vmcnt(0) guarantees arrival.
// State ~110 regs -> launch_bounds(256,4) fits 128 without spills
// -> 4 blocks/CU = 16 waves/CU.
__global__ __launch_bounds__(256, 4) void attn_kernel(
    const u16* __restrict__ Qw, const u16* __restrict__ Kw, const u16* __restrict__ Vtw,
    const float* __restrict__ pb, const float* __restrict__ mk, u16* __restrict__ Out) {
  __shared__ __align__(16) u16 Ksm[2][64 * 64];
  __shared__ __align__(16) u16 Vsm[2][64 * 64];
  __shared__ __align__(16) u16 Psm[4 * 16 * 64];  // per-wave, XOR-swizzled

  const int qt = blockIdx.x >> 1;  // 0..31
  const int b  = blockIdx.x & 1;   // batch
  const int h  = blockIdx.y;       // 0..15
  const int t = threadIdx.x;
  const int lane = t & 63;
  const int wid = t >> 6;
  const int l15 = lane & 15, lg = lane >> 4;
  const size_t bh = (size_t)b * 16 + h;

  const u16* kbase = Kw + bh * 2048 * 64;
  const u16* vbase = Vtw + bh * 64 * 2048;

  // Q A-fragments (kept in registers across all kv tiles)
  const int qrow_a = qt * 64 + wid * 16 + l15;
  const u16* qptr = Qw + (bh * 2048 + (size_t)qrow_a) * 64 + lg * 8;
  const s16x8 qf0 = *(const s16x8*)(qptr);
  const s16x8 qf1 = *(const s16x8*)(qptr + 32);

  const int qrow_c = qt * 64 + wid * 16 + lg * 4;  // C-layout base q row
  const float* pb_base = pb + ((size_t)h * 2048 + qrow_c) * 2048;
  const float* mk_base = mk + ((size_t)b * 2048 + qrow_c) * 2048;

  const float C1 = 0.125f * 1.4426950408889634f;  // exp2-domain logit scale

  f32x4 oacc[4] = {};
  float m_r[4], l_r[4];
  #pragma unroll
  for (int r = 0; r < 4; ++r) { m_r[r] = -3.0e38f; l_r[r] = 0.f; }

  f32x4 pbmk[4];  // C-init: pb + 8*mask, fragment layout

#define STAGE(KT, BI)                                                          \
  {                                                                            \
    const int kv0_ = (KT) * 64;                                                \
    _Pragma("unroll")                                                          \
    for (int i = 0; i < 2; ++i) {                                              \
      int tt = i * 256 + t;                                                    \
      int row = tt >> 3;                                                       \
      int sg = (tt & 7) ^ (row & 7);                                           \
      gll16(kbase + (size_t)(kv0_ + row) * 64 + sg * 8, &Ksm[BI][tt * 8]);     \
      gll16(vbase + (size_t)row * 2048 + kv0_ + sg * 8, &Vsm[BI][tt * 8]);     \
    }                                                                          \
  }

#define LOADPBMK(KT)                                                           \
  {                                                                            \
    const int kv0_ = (KT) * 64;                                                \
    _Pragma("unroll")                                                          \
    for (int f = 0; f < 4; ++f) {                                              \
      _Pragma("unroll")                                                        \
      for (int r = 0; r < 4; ++r) {                                            \
        size_t off = (size_t)r * 2048 + kv0_ + f * 16 + l15;                   \
        pbmk[f][r] = fmaf(mk_base[off], 8.0f, pb_base[off]);                   \
      }                                                                        \
    }                                                                          \
  }

  STAGE(0, 0);
  LOADPBMK(0);

  for (int kt = 0; kt < 32; ++kt) {
    const int bi = kt & 1;

    __syncthreads();  // drains stage(kt)+pbmk(kt), issued one phase ago

    if (kt < 31) STAGE(kt + 1, bi ^ 1);

    // QK^T round 0: C = pbmk (hardware adds bias+mask for free)
    f32x4 sf[4];
    #pragma unroll
    for (int f = 0; f < 4; ++f) {
      int row = f * 16 + l15;
      int g = lg ^ (row & 7);
      s16x8 kf = *(const s16x8*)(&Ksm[bi][row * 64 + g * 8]);
      sf[f] = MFMA16(qf0, kf, pbmk[f]);
    }

    // pbmk consumed -> reload for next tile (covered by full compute phase)
    if (kt < 31) LOADPBMK(kt + 1);

    // QK^T round 1
    #pragma unroll
    for (int f = 0; f < 4; ++f) {
      int row = f * 16 + l15;
      int g = (lg + 4) ^ (row & 7);
      s16x8 kf = *(const s16x8*)(&Ksm[bi][row * 64 + g * 8]);
      sf[f] = MFMA16(qf1, kf, sf[f]);
    }

    // lv (exp2 domain) = sf * C1 ; tile row-max
    float pmax[4];
    #pragma unroll
    for (int r = 0; r < 4; ++r) pmax[r] = -3.0e38f;
    #pragma unroll
    for (int f = 0; f < 4; ++f) {
      #pragma unroll
      for (int r = 0; r < 4; ++r) {
        float lv = sf[f][r] * C1;
        sf[f][r] = lv;
        pmax[r] = fmaxf(pmax[r], lv);
      }
    }
    #pragma unroll
    for (int off = 1; off < 16; off <<= 1) {
      #pragma unroll
      for (int r = 0; r < 4; ++r) pmax[r] = fmaxf(pmax[r], __shfl_xor(pmax[r], off));
    }
    float corr[4], rsum[4];
    #pragma unroll
    for (int r = 0; r < 4; ++r) {
      float mn = fmaxf(m_r[r], pmax[r]);
      corr[r] = exp2f(m_r[r] - mn);
      m_r[r] = mn;
      rsum[r] = 0.f;
    }
    #pragma unroll
    for (int f = 0; f < 4; ++f) {
      #pragma unroll
      for (int r = 0; r < 4; ++r) {
        float p = exp2f(sf[f][r] - m_r[r]);
        sf[f][r] = p;
        rsum[r] += p;
      }
    }
    #pragma unroll
    for (int off = 1; off < 16; off <<= 1) {
      #pragma unroll
      for (int r = 0; r < 4; ++r) rsum[r] += __shfl_xor(rsum[r], off);
    }
    #pragma unroll
    for (int r = 0; r < 4; ++r) l_r[r] = l_r[r] * corr[r] + rsum[r];
    #pragma unroll
    for (int f = 0; f < 4; ++f) {
      #pragma unroll
      for (int r = 0; r < 4; ++r) oacc[f][r] *= corr[r];
    }

    // P -> bf16 -> per-wave LDS, stride 64 with XOR group swizzle (0 conflicts)
    u16* pw = Psm + wid * 1024;
    #pragma unroll
    for (int f = 0; f < 4; ++f) {
      #pragma unroll
      for (int r = 0; r < 4; ++r) {
        int prow = lg * 4 + r;
        int c = f * 16 + l15;
        pw[prow * 64 + (((c >> 3) ^ (prow & 7)) * 8) + (c & 7)] = f2bf(sf[f][r]);
      }
    }

    // O += P.V  (V from transposed-layout tile, k-contiguous)
    #pragma unroll
    for (int kk = 0; kk < 2; ++kk) {
      int pg = (kk * 4 + lg) ^ (l15 & 7);
      s16x8 pf = *(const s16x8*)(pw + l15 * 64 + pg * 8);
      #pragma unroll
      for (int f = 0; f < 4; ++f) {
        int row = f * 16 + l15;
        int g = (lg + 4 * kk) ^ (row & 7);
        s16x8 vf = *(const s16x8*)(&Vsm[bi][row * 64 + g * 8]);
        oacc[f] = MFMA16(pf, vf, oacc[f]);
      }
    }
  }
#undef LOADPBMK
#undef STAGE

  #pragma unroll
  for (int r = 0; r < 4; ++r) {
    float inv = 1.f / l_r[r];
    #pragma unroll
    for (int f = 0; f < 4; ++f) {
      int q = qrow_c + r;
      Out[((size_t)b * 2048 + q) * 1024 + h * 64 + f * 16 + l15] =
          f2bf(oacc[f][r] * inv);
    }
  }
}

// ---------------- output projection GEMM ----------------
__global__ __launch_bounds__(256) void oproj_kernel(
    const u16* __restrict__ A, const u16* __restrict__ W,
    const float* __restrict__ bias, float* __restrict__ out) {
  __shared__ __align__(16) u16 Asm[128 * 64];
  __shared__ __align__(16) u16 Bsm[128 * 64];

  const int t = threadIdx.x;
  const int lane = t & 63;
  const int l15 = lane & 15, lg = lane >> 4;
  const int wid = t >> 6;
  const int wr = wid >> 1, wc = wid & 1;
  const int m0 = blockIdx.x * 128, n0 = blockIdx.y * 128;

  f32x4 acc[4][4] = {};

  for (int kt = 0; kt < 16; ++kt) {
    __syncthreads();
    #pragma unroll
    for (int i = 0; i < 4; ++i) {
      int tt = i * 256 + t;
      int row = tt >> 3;
      int sg = (tt & 7) ^ (row & 7);
      gll16(A + (size_t)(m0 + row) * 1024 + kt * 64 + sg * 8, Asm + tt * 8);
    }
    #pragma unroll
    for (int i = 0; i < 4; ++i) {
      int tt = i * 256 + t;
      int row = tt >> 3;
      int sg = (tt & 7) ^ (row & 7);
      gll16(W + (size_t)(n0 + row) * 1024 + kt * 64 + sg * 8, Bsm + tt * 8);
    }
    __syncthreads();
    #pragma unroll
    for (int kk = 0; kk < 2; ++kk) {
      s16x8 af[4], bf[4];
      #pragma unroll
      for (int mi = 0; mi < 4; ++mi) {
        int row = wr * 64 + mi * 16 + l15;
        int g = (lg + 4 * kk) ^ (row & 7);
        af[mi] = *(const s16x8*)(Asm + row * 64 + g * 8);
      }
      #pragma unroll
      for (int ni = 0; ni < 4; ++ni) {
        int row = wc * 64 + ni * 16 + l15;
        int g = (lg + 4 * kk) ^ (row & 7);
        bf[ni] = *(const s16x8*)(Bsm + row * 64 + g * 8);
      }
      #pragma unroll
      for (int mi = 0; mi < 4; ++mi)
        #pragma unroll
        for (int ni = 0; ni < 4; ++ni)
          acc[mi][ni] = MFMA16(af[mi], bf[ni], acc[mi][ni]);
    }
  }

  #pragma unroll
  for (int ni = 0; ni < 4; ++ni) {
    const int col = n0 + wc * 64 + ni * 16 + l15;
    const float bval = bias[col];
    #pragma unroll
    for (int mi = 0; mi < 4; ++mi) {
      const int row0 = m0 + wr * 64 + mi * 16 + lg * 4;
      #pragma unroll
      for (int r = 0; r < 4; ++r)
        out[(size_t)(row0 + r) * 1024 + col] = acc[mi][ni][r] + bval;
    }
  }
}

extern "C" void kernel_launch(void* const* d_in, const int* in_sizes, int n_in,
                              void* d_out, int out_size, void* d_ws, size_t ws_size,
                              hipStream_t stream) {
  const float* query = (const float*)d_in[0];
  const float* key_i = (const float*)d_in[1];
  const float* value = (const float*)d_in[2];
  const float* mask  = (const float*)d_in[3];
  const float* pbias = (const float*)d_in[4];
  const float* wq = (const float*)d_in[5];
  const float* bq = (const float*)d_in[6];
  const float* wk = (const float*)d_in[7];
  const float* bk = (const float*)d_in[8];
  const float* wv = (const float*)d_in[9];
  const float* bv = (const float*)d_in[10];
  const float* wo = (const float*)d_in[11];
  const float* bo = (const float*)d_in[12];
  float* out = (float*)d_out;

  uint8_t* ws = (uint8_t*)d_ws;
  u16* Xq = (u16*)(ws + 0);          // 4096x1024 bf16
  u16* Xk = (u16*)(ws + 8388608);
  u16* Xv = (u16*)(ws + 16777216);
  u16* Wq = (u16*)(ws + 25165824);   // 1024x1024 bf16 each
  u16* Wk = (u16*)(ws + 27262976);
  u16* Wv = (u16*)(ws + 29360128);
  u16* Wo = (u16*)(ws + 31457280);
  u16* Qw = (u16*)(ws + 33554432);   // [B,H,S,D] bf16
  u16* Kw = (u16*)(ws + 41943040);   // [B,H,S,D]
  u16* Vt = (u16*)(ws + 50331648);   // [B,H,D,S]
  u16* Aw = (u16*)(ws + 58720256);   // [B,S,H*D]

  cvt_all_kernel<<<16384, 256, 0, stream>>>(
      (const f32x4*)query, (const f32x4*)key_i, (const f32x4*)value,
      (const f32x4*)wq, (const f32x4*)wk, (const f32x4*)wv, (const f32x4*)wo,
      (u16x4*)Xq);

  proj_qkv_kernel<<<dim3(32, 8, 3), 256, 0, stream>>>(Xq, Xk, Xv, Wq, Wk, Wv,
                                                      bq, bk, bv, Qw, Kw, Vt);
  attn_kernel<<<dim3(64, 16), 256, 0, stream>>>(Qw, Kw, Vt, pbias, mask, Aw);
  oproj_kernel<<<dim3(32, 8), 256, 0, stream>>>(Aw, Wo, bo, out);
}

// Round 10
// 261.803 us; speedup vs baseline: 1.6119x; 1.0341x over previous
//
#include <hip/hip_runtime.h>
#include <hip/hip_bf16.h>
#include <cstdint>

typedef unsigned short u16;
typedef __attribute__((ext_vector_type(8))) short s16x8;
typedef __attribute__((ext_vector_type(4))) float f32x4;
typedef __attribute__((ext_vector_type(4))) unsigned short u16x4;

#define MFMA16(a, b, c) __builtin_amdgcn_mfma_f32_16x16x32_bf16((a), (b), (c), 0, 0, 0)

__device__ __forceinline__ u16 f2bf(float f) {
  union { float f; uint32_t u; } x; x.f = f;
  uint32_t u = x.u;
  return (u16)((u + 0x7fffu + ((u >> 16) & 1u)) >> 16);
}

__device__ __forceinline__ void gll16(const void* gsrc, void* ldst) {
  __builtin_amdgcn_global_load_lds(
      (const __attribute__((address_space(1))) uint32_t*)(uintptr_t)gsrc,
      (__attribute__((address_space(3))) uint32_t*)(uintptr_t)ldst, 16, 0, 0);
}

// ---------------- fused f32 -> bf16 conversion (one launch for all 7 tensors)
__global__ __launch_bounds__(256) void cvt_all_kernel(
    const f32x4* __restrict__ q, const f32x4* __restrict__ k, const f32x4* __restrict__ v,
    const f32x4* __restrict__ wq, const f32x4* __restrict__ wk,
    const f32x4* __restrict__ wv, const f32x4* __restrict__ wo,
    u16x4* __restrict__ dst) {
  int i = blockIdx.x * 256 + threadIdx.x;  // 0 .. 4194303
  int r = i >> 18;                         // 262144-element chunks
  const f32x4* src;
  int off;
  if (r < 4)       { src = q;  off = 0; }
  else if (r < 8)  { src = k;  off = 1048576; }
  else if (r < 12) { src = v;  off = 2097152; }
  else if (r == 12){ src = wq; off = 3145728; }
  else if (r == 13){ src = wk; off = 3407872; }
  else if (r == 14){ src = wv; off = 3670016; }
  else             { src = wo; off = 3932160; }
  f32x4 val = src[i - off];
  u16x4 o;
  #pragma unroll
  for (int j = 0; j < 4; ++j) o[j] = f2bf(val[j]);
  dst[i] = o;
}

// ---------------- fused QKV projection GEMM (bf16 in via gll16) ------------
__global__ __launch_bounds__(256) void proj_qkv_kernel(
    const u16* __restrict__ Xq, const u16* __restrict__ Xk, const u16* __restrict__ Xv,
    const u16* __restrict__ Wq, const u16* __restrict__ Wk, const u16* __restrict__ Wv,
    const float* __restrict__ bq, const float* __restrict__ bk, const float* __restrict__ bv,
    u16* __restrict__ Qo, u16* __restrict__ Ko, u16* __restrict__ Vo) {
  __shared__ __align__(16) u16 Asm[128 * 64];
  __shared__ __align__(16) u16 Bsm[128 * 64];

  const int z = blockIdx.z;
  const u16* X = (z == 0) ? Xq : (z == 1) ? Xk : Xv;
  const u16* W = (z == 0) ? Wq : (z == 1) ? Wk : Wv;
  const float* bias = (z == 0) ? bq : (z == 1) ? bk : bv;

  const int t = threadIdx.x;
  const int lane = t & 63;
  const int l15 = lane & 15, lg = lane >> 4;
  const int wid = t >> 6;
  const int wr = wid >> 1, wc = wid & 1;
  const int m0 = blockIdx.x * 128, n0 = blockIdx.y * 128;

  f32x4 acc[4][4] = {};

  for (int kt = 0; kt < 16; ++kt) {
    __syncthreads();
    #pragma unroll
    for (int i = 0; i < 4; ++i) {
      int tt = i * 256 + t;
      int row = tt >> 3;
      int sg = (tt & 7) ^ (row & 7);
      gll16(X + (size_t)(m0 + row) * 1024 + kt * 64 + sg * 8, Asm + tt * 8);
    }
    #pragma unroll
    for (int i = 0; i < 4; ++i) {
      int tt = i * 256 + t;
      int row = tt >> 3;
      int sg = (tt & 7) ^ (row & 7);
      gll16(W + (size_t)(n0 + row) * 1024 + kt * 64 + sg * 8, Bsm + tt * 8);
    }
    __syncthreads();
    #pragma unroll
    for (int kk = 0; kk < 2; ++kk) {
      s16x8 af[4], bf[4];
      #pragma unroll
      for (int mi = 0; mi < 4; ++mi) {
        int row = wr * 64 + mi * 16 + l15;
        int g = (lg + 4 * kk) ^ (row & 7);
        af[mi] = *(const s16x8*)(Asm + row * 64 + g * 8);
      }
      #pragma unroll
      for (int ni = 0; ni < 4; ++ni) {
        int row = wc * 64 + ni * 16 + l15;
        int g = (lg + 4 * kk) ^ (row & 7);
        bf[ni] = *(const s16x8*)(Bsm + row * 64 + g * 8);
      }
      #pragma unroll
      for (int mi = 0; mi < 4; ++mi)
        #pragma unroll
        for (int ni = 0; ni < 4; ++ni)
          acc[mi][ni] = MFMA16(af[mi], bf[ni], acc[mi][ni]);
    }
  }

  #pragma unroll
  for (int ni = 0; ni < 4; ++ni) {
    const int col = n0 + wc * 64 + ni * 16 + l15;
    const int h = col >> 6, d = col & 63;
    const float bval = bias[col];
    #pragma unroll
    for (int mi = 0; mi < 4; ++mi) {
      const int row0 = m0 + wr * 64 + mi * 16 + lg * 4;
      const int bb = row0 >> 11, s0 = row0 & 2047;
      if (z == 2) {
        u16x4 pk;
        #pragma unroll
        for (int r = 0; r < 4; ++r) pk[r] = f2bf(acc[mi][ni][r] + bval);
        *(u16x4*)(Vo + ((size_t)(bb * 16 + h) * 64 + d) * 2048 + s0) = pk;
      } else {
        u16* dst = (z == 0) ? Qo : Ko;
        #pragma unroll
        for (int r = 0; r < 4; ++r)
          dst[((size_t)(bb * 16 + h) * 2048 + (s0 + r)) * 64 + d] =
              f2bf(acc[mi][ni][r] + bval);
      }
    }
  }
}

// ---------------- flash attention, swapped-QK^T / compact-LDS P ------------
// S^T = mfma(K, Q) with C = pb + 8*mask -> lane owns P^T[kv=f*16+lg*4+r][q=l15]
// so m/l/corr/O are lane-local; cross-group reduce = 2 shfl_xor (16/32).
// P^T -> LDS [q][kv] (4x ds_write_b64, 16B-chunk XOR swizzle) -> PV B-operand
// read = 2x ds_read_b128. O^T = mfma(V^T, P^T). LDS-pipe ops/wave/iter:
// 8 (K) + 8 (V) + 4 (Pw) + 2 (Pr) + 4 (shfl) = 26 vs 66 in rounds 2-8.
__global__ __launch_bounds__(256, 4) void attn_kernel(
    const u16* __restrict__ Qw, const u16* __restrict__ Kw, const u16* __restrict__ Vtw,
    const float* __restrict__ pb, const float* __restrict__ mk, u16* __restrict__ Out) {
  __shared__ __align__(16) u16 Ksm[2][64 * 64];
  __shared__ __align__(16) u16 Vsm[2][64 * 64];
  __shared__ __align__(16) u16 Psm[4 * 16 * 64];  // per-wave [q=16][kv=64]

  const int qt = blockIdx.x >> 1;  // 0..31
  const int b  = blockIdx.x & 1;   // batch
  const int h  = blockIdx.y;       // 0..15
  const int t = threadIdx.x;
  const int lane = t & 63;
  const int wid = t >> 6;
  const int l15 = lane & 15, lg = lane >> 4;
  const size_t bh = (size_t)b * 16 + h;

  const u16* kbase = Kw + bh * 2048 * 64;
  const u16* vbase = Vtw + bh * 64 * 2048;

  // this lane's q row (swapped scheme: q lives on l15 everywhere)
  const int qrow = qt * 64 + wid * 16 + l15;

  // Q as B-operand fragments: B[k=d][col=q=l15] = Q[qrow][d = lg*8+j (+32)]
  const u16* qptr = Qw + (bh * 2048 + (size_t)qrow) * 64 + lg * 8;
  const s16x8 qf0 = *(const s16x8*)(qptr);
  const s16x8 qf1 = *(const s16x8*)(qptr + 32);

  const float* pb_q = pb + ((size_t)h * 2048 + qrow) * 2048;
  const float* mk_q = mk + ((size_t)b * 2048 + qrow) * 2048;

  const float C1 = 0.125f * 1.4426950408889634f;  // exp2-domain logit scale

  f32x4 oaccT[4] = {};              // O^T[d = f*16+lg*4+r][q = l15]
  float m_r = -3.0e38f, l_r = 0.f;  // per-lane (per-q) stats

  f32x4 pb4[4], mk4[4];  // next tile's pb / mask fragments (dwordx4 loads)

  u16* pw = Psm + wid * 1024;  // this wave's P buffer, u16 units

#define STAGE(KT, BI)                                                          \
  {                                                                            \
    const int kv0_ = (KT) * 64;                                                \
    _Pragma("unroll")                                                          \
    for (int i = 0; i < 2; ++i) {                                              \
      int tt = i * 256 + t;                                                    \
      int row = tt >> 3;                                                       \
      int sg = (tt & 7) ^ (row & 7);                                           \
      gll16(kbase + (size_t)(kv0_ + row) * 64 + sg * 8, &Ksm[BI][tt * 8]);     \
      gll16(vbase + (size_t)row * 2048 + kv0_ + sg * 8, &Vsm[BI][tt * 8]);     \
    }                                                                          \
  }

#define LOADPM(KT)                                                             \
  {                                                                            \
    const int kv0_ = (KT) * 64;                                                \
    _Pragma("unroll")                                                          \
    for (int f = 0; f < 4; ++f) {                                              \
      pb4[f] = *(const f32x4*)(pb_q + kv0_ + f * 16 + lg * 4);                 \
      mk4[f] = *(const f32x4*)(mk_q + kv0_ + f * 16 + lg * 4);                 \
    }                                                                          \
  }

  STAGE(0, 0);
  LOADPM(0);

  for (int kt = 0; kt < 32; ++kt) {
    const int bi = kt & 1;

    __syncthreads();  // drains stage(kt) + pb/mk(kt), issued one phase ago

    if (kt < 31) STAGE(kt + 1, bi ^ 1);

    // S^T = K.Q^T with C = pb + 8*mask : D[row=kv(lg*4+r within f)][col=q=l15]
    f32x4 sfT[4];
    #pragma unroll
    for (int f = 0; f < 4; ++f) {
      int row = f * 16 + l15;
      int g = lg ^ (row & 7);
      s16x8 kf = *(const s16x8*)(&Ksm[bi][row * 64 + g * 8]);
      f32x4 c;
      #pragma unroll
      for (int r = 0; r < 4; ++r) c[r] = fmaf(mk4[f][r], 8.0f, pb4[f][r]);
      sfT[f] = MFMA16(kf, qf0, c);
    }
    #pragma unroll
    for (int f = 0; f < 4; ++f) {
      int row = f * 16 + l15;
      int g = (lg + 4) ^ (row & 7);
      s16x8 kf = *(const s16x8*)(&Ksm[bi][row * 64 + g * 8]);
      sfT[f] = MFMA16(kf, qf1, sfT[f]);
    }

    // pb/mk consumed -> prefetch next tile's (full compute phase of cover)
    if (kt < 31) LOADPM(kt + 1);

    // logits (exp2 domain) + lane-local max, reduce across lg groups (2 shfl)
    float pmax = -3.0e38f;
    #pragma unroll
    for (int f = 0; f < 4; ++f) {
      #pragma unroll
      for (int r = 0; r < 4; ++r) {
        float lv = sfT[f][r] * C1;
        sfT[f][r] = lv;
        pmax = fmaxf(pmax, lv);
      }
    }
    pmax = fmaxf(pmax, __shfl_xor(pmax, 16));
    pmax = fmaxf(pmax, __shfl_xor(pmax, 32));

    // rescale only when the running max actually grows (exact)
    if (__any(pmax > m_r)) {
      float mn = fmaxf(m_r, pmax);
      float corr = exp2f(m_r - mn);
      m_r = mn;
      l_r *= corr;
      #pragma unroll
      for (int f = 0; f < 4; ++f)
        #pragma unroll
        for (int r = 0; r < 4; ++r) oaccT[f][r] *= corr;
    }

    float rsum = 0.f;
    #pragma unroll
    for (int f = 0; f < 4; ++f) {
      #pragma unroll
      for (int r = 0; r < 4; ++r) {
        float p = exp2f(sfT[f][r] - m_r);
        sfT[f][r] = p;
        rsum += p;
      }
    }
    rsum += __shfl_xor(rsum, 16);
    rsum += __shfl_xor(rsum, 32);
    l_r += rsum;

    // P^T -> LDS [q=l15][kv]: lane's 4 kv-consecutive values per f are one
    // ds_write_b64. 16B-chunk XOR swizzle (c ^ (l15&7)) balances banks and is
    // inverted identically on the read side.
    #pragma unroll
    for (int f = 0; f < 4; ++f) {
      u16x4 pk4;
      #pragma unroll
      for (int r = 0; r < 4; ++r) pk4[r] = f2bf(sfT[f][r]);
      int csw = (f * 2 + (lg >> 1)) ^ (l15 & 7);
      *(u16x4*)(pw + l15 * 64 + csw * 8 + (lg & 1) * 4) = pk4;
    }

    // O^T += V^T . P^T  (A = V^T from Vsm, B = P^T from pw)
    #pragma unroll
    for (int kk = 0; kk < 2; ++kk) {
      int pc = (kk * 4 + lg) ^ (l15 & 7);
      s16x8 pf = *(const s16x8*)(pw + l15 * 64 + pc * 8);  // b128
      #pragma unroll
      for (int f = 0; f < 4; ++f) {
        int row = f * 16 + l15;
        int g = (lg + 4 * kk) ^ (row & 7);
        s16x8 vf = *(const s16x8*)(&Vsm[bi][row * 64 + g * 8]);
        oaccT[f] = MFMA16(vf, pf, oaccT[f]);
      }
    }
  }
#undef LOADPM
#undef STAGE

  // epilogue: all per-lane (q = l15); d = f*16 + lg*4 + r
  const float inv = 1.f / l_r;
  #pragma unroll
  for (int f = 0; f < 4; ++f) {
    u16x4 pk;
    #pragma unroll
    for (int r = 0; r < 4; ++r) pk[r] = f2bf(oaccT[f][r] * inv);
    *(u16x4*)(Out + ((size_t)b * 2048 + qrow) * 1024 + h * 64 + f * 16 + lg * 4) = pk;
  }
}

// ---------------- output projection GEMM ----------------
__global__ __launch_bounds__(256) void oproj_kernel(
    const u16* __restrict__ A, const u16* __restrict__ W,
    const float* __restrict__ bias, float* __restrict__ out) {
  __shared__ __align__(16) u16 Asm[128 * 64];
  __shared__ __align__(16) u16 Bsm[128 * 64];

  const int t = threadIdx.x;
  const int lane = t & 63;
  const int l15 = lane & 15, lg = lane >> 4;
  const int wid = t >> 6;
  const int wr = wid >> 1, wc = wid & 1;
  const int m0 = blockIdx.x * 128, n0 = blockIdx.y * 128;

  f32x4 acc[4][4] = {};

  for (int kt = 0; kt < 16; ++kt) {
    __syncthreads();
    #pragma unroll
    for (int i = 0; i < 4; ++i) {
      int tt = i * 256 + t;
      int row = tt >> 3;
      int sg = (tt & 7) ^ (row & 7);
      gll16(A + (size_t)(m0 + row) * 1024 + kt * 64 + sg * 8, Asm + tt * 8);
    }
    #pragma unroll
    for (int i = 0; i < 4; ++i) {
      int tt = i * 256 + t;
      int row = tt >> 3;
      int sg = (tt & 7) ^ (row & 7);
      gll16(W + (size_t)(n0 + row) * 1024 + kt * 64 + sg * 8, Bsm + tt * 8);
    }
    __syncthreads();
    #pragma unroll
    for (int kk = 0; kk < 2; ++kk) {
      s16x8 af[4], bf[4];
      #pragma unroll
      for (int mi = 0; mi < 4; ++mi) {
        int row = wr * 64 + mi * 16 + l15;
        int g = (lg + 4 * kk) ^ (row & 7);
        af[mi] = *(const s16x8*)(Asm + row * 64 + g * 8);
      }
      #pragma unroll
      for (int ni = 0; ni < 4; ++ni) {
        int row = wc * 64 + ni * 16 + l15;
        int g = (lg + 4 * kk) ^ (row & 7);
        bf[ni] = *(const s16x8*)(Bsm + row * 64 + g * 8);
      }
      #pragma unroll
      for (int mi = 0; mi < 4; ++mi)
        #pragma unroll
        for (int ni = 0; ni < 4; ++ni)
          acc[mi][ni] = MFMA16(af[mi], bf[ni], acc[mi][ni]);
    }
  }

  #pragma unroll
  for (int ni = 0; ni < 4; ++ni) {
    const int col = n0 + wc * 64 + ni * 16 + l15;
    const float bval = bias[col];
    #pragma unroll
    for (int mi = 0; mi < 4; ++mi) {
      const int row0 = m0 + wr * 64 + mi * 16 + lg * 4;
      #pragma unroll
      for (int r = 0; r < 4; ++r)
        out[(size_t)(row0 + r) * 1024 + col] = acc[mi][ni][r] + bval;
    }
  }
}

extern "C" void kernel_launch(void* const* d_in, const int* in_sizes, int n_in,
                              void* d_out, int out_size, void* d_ws, size_t ws_size,
                              hipStream_t stream) {
  const float* query = (const float*)d_in[0];
  const float* key_i = (const float*)d_in[1];
  const float* value = (const float*)d_in[2];
  const float* mask  = (const float*)d_in[3];
  const float* pbias = (const float*)d_in[4];
  const float* wq = (const float*)d_in[5];
  const float* bq = (const float*)d_in[6];
  const float* wk = (const float*)d_in[7];
  const float* bk = (const float*)d_in[8];
  const float* wv = (const float*)d_in[9];
  const float* bv = (const float*)d_in[10];
  const float* wo = (const float*)d_in[11];
  const float* bo = (const float*)d_in[12];
  float* out = (float*)d_out;

  uint8_t* ws = (uint8_t*)d_ws;
  u16* Xq = (u16*)(ws + 0);          // 4096x1024 bf16
  u16* Xk = (u16*)(ws + 8388608);
  u16* Xv = (u16*)(ws + 16777216);
  u16* Wq = (u16*)(ws + 25165824);   // 1024x1024 bf16 each
  u16* Wk = (u16*)(ws + 27262976);
  u16* Wv = (u16*)(ws + 29360128);
  u16* Wo = (u16*)(ws + 31457280);
  u16* Qw = (u16*)(ws + 33554432);   // [B,H,S,D] bf16
  u16* Kw = (u16*)(ws + 41943040);   // [B,H,S,D]
  u16* Vt = (u16*)(ws + 50331648);   // [B,H,D,S]
  u16* Aw = (u16*)(ws + 58720256);   // [B,S,H*D]

  cvt_all_kernel<<<16384, 256, 0, stream>>>(
      (const f32x4*)query, (const f32x4*)key_i, (const f32x4*)value,
      (const f32x4*)wq, (const f32x4*)wk, (const f32x4*)wv, (const f32x4*)wo,
      (u16x4*)Xq);

  proj_qkv_kernel<<<dim3(32, 8, 3), 256, 0, stream>>>(Xq, Xk, Xv, Wq, Wk, Wv,
                                                      bq, bk, bv, Qw, Kw, Vt);
  attn_kernel<<<dim3(64, 16), 256, 0, stream>>>(Qw, Kw, Vt, pbias, mask, Aw);
  oproj_kernel<<<dim3(32, 8), 256, 0, stream>>>(Aw, Wo, bo, out);
}